// Round 2
// baseline (141.208 us; speedup 1.0000x reference)
//
#include <hip/hip_runtime.h>

// GATraj fused kernels for MI355X (gfx950) — round 2.
//
// Math simplifications (verified passing in round 1):
//  * LN over the size-1 W_a channel == be_a exactly -> Pos is uniform 1/cnt_i
//    over masked neighbors (exp(-10000) == 0 in f32). W_a/b_a/g_a unused.
//  * tmp @ W_g = r@Wg[0:64] + h_i@Wg[64:128] + h_j@Wg[128:192]; the latter two
//    are per-node precomputes (A_pre includes b_g).
//  * LN of (c0*w0 + c1*w1 + b_r) is analytic: mean/var are a quadratic form in
//    (c0,c1) with 6 precomputed moments of centered W_r columns.
//
// Round-2 structural change: the per-row fat block (4 waves + 2 barriers/chunk,
// occupancy 21.7%, VALUBusy 44%) is replaced by SINGLE-WAVE blocks, one
// 64-pair chunk each (grid 768x12, early-exit on empty chunks). No cross-wave
// barriers; partial H sums go to a deterministic per-chunk buffer, reduced in
// a small final kernel.

#define NN 768
#define DD 64
#define NCH 12  // ceil(768/64) chunks per row max
#define EPSF 1e-5f

typedef __attribute__((ext_vector_type(8))) short short8;
typedef __attribute__((ext_vector_type(4))) float float4v;

__device__ __forceinline__ unsigned short f2bf(float f) {
  unsigned int u = __float_as_uint(f);
  u += 0x7fffu + ((u >> 16) & 1u);  // round-to-nearest-even
  return (unsigned short)(u >> 16);
}

// ---------------------------------------------------------------------------
// Prep kernel, grid = 768 + 1 + 192 blocks x 256 threads:
//   bid < 768   : compact masked-j list for row bid -> Lst, cnt_g
//   bid == 768  : W_r centered columns + moments; bf16 transposed Wg_lo pack
//   bid > 768   : A_pre/B_pre GEMVs, 4 rows per block (wave per row)
// ---------------------------------------------------------------------------
__global__ __launch_bounds__(256) void prep_kernel(
    const float* __restrict__ hidden, const float* __restrict__ Wg,
    const float* __restrict__ bg, const float* __restrict__ Wr,
    const float* __restrict__ br, const int* __restrict__ nei,
    float* __restrict__ A_pre, float* __restrict__ B_pre,
    float* __restrict__ w0h, float* __restrict__ w1h, float* __restrict__ bh,
    float* __restrict__ evec, unsigned short* __restrict__ WgT,
    unsigned short* __restrict__ Lst, int* __restrict__ cnt_g) {
  const int bid = blockIdx.x;
  const int tid = threadIdx.x;

  if (bid < NN) {
    __shared__ int cLds;
    if (tid == 0) cLds = 0;
    __syncthreads();
#pragma unroll
    for (int rep = 0; rep < 3; ++rep) {
      int jj = tid + rep * 256;
      if (nei[bid * NN + jj] > 0) {
        int idx = atomicAdd(&cLds, 1);
        Lst[bid * NN + idx] = (unsigned short)jj;
      }
    }
    __syncthreads();
    if (tid == 0) cnt_g[bid] = cLds;
    return;
  }

  if (bid == NN) {
    // Transposed bf16 pack of Wg rows 0..63: WgT[n*64+k] = bf16(Wg[k*64+n])
    for (int idx = tid; idx < DD * DD; idx += 256) {
      int n = idx >> 6, k = idx & 63;
      WgT[idx] = f2bf(Wg[k * DD + n]);
    }
    if (tid < 64) {  // wave 0: W_r moments
      int t = tid;
      float w0 = Wr[t], w1 = Wr[DD + t], bb = br[t];
      float m0 = w0, m1 = w1, mb = bb;
      for (int m = 1; m < 64; m <<= 1) {
        m0 += __shfl_xor(m0, m);
        m1 += __shfl_xor(m1, m);
        mb += __shfl_xor(mb, m);
      }
      m0 *= (1.f / DD);
      m1 *= (1.f / DD);
      mb *= (1.f / DD);
      float a0 = w0 - m0, a1 = w1 - m1, ab = bb - mb;
      w0h[t] = a0;
      w1h[t] = a1;
      bh[t] = ab;
      float e00 = a0 * a0, e11 = a1 * a1, ebb = ab * ab;
      float e01 = a0 * a1, e0b = a0 * ab, e1b = a1 * ab;
      for (int m = 1; m < 64; m <<= 1) {
        e00 += __shfl_xor(e00, m);
        e11 += __shfl_xor(e11, m);
        ebb += __shfl_xor(ebb, m);
        e01 += __shfl_xor(e01, m);
        e0b += __shfl_xor(e0b, m);
        e1b += __shfl_xor(e1b, m);
      }
      if (t == 0) {
        evec[0] = e00 * (1.f / DD);
        evec[1] = e11 * (1.f / DD);
        evec[2] = ebb * (1.f / DD);
        evec[3] = e01 * (1.f / DD);
        evec[4] = e0b * (1.f / DD);
        evec[5] = e1b * (1.f / DD);
      }
    }
    return;
  }

  // A_pre / B_pre: 4 rows per block, one wave per row.
  const int w = tid >> 6;
  const int lane = tid & 63;
  const int i = (bid - NN - 1) * 4 + w;
  float hv = hidden[i * DD + lane];
  float a = bg[lane];
  float b = 0.f;
#pragma unroll 8
  for (int k = 0; k < DD; ++k) {
    float hk = __shfl(hv, k);
    a = fmaf(hk, Wg[(DD + k) * DD + lane], a);
    b = fmaf(hk, Wg[(2 * DD + k) * DD + lane], b);
  }
  A_pre[i * DD + lane] = a;
  B_pre[i * DD + lane] = b;
}

// ---------------------------------------------------------------------------
// Pair kernel: one wave (64 threads) per (row i, chunk c). grid = 768*12.
// ---------------------------------------------------------------------------
__global__ __launch_bounds__(64) void pair_kernel(
    const float* __restrict__ corr, const float* __restrict__ hidden,
    const float* __restrict__ gr, const float* __restrict__ ber,
    const float* __restrict__ gg, const float* __restrict__ beg,
    const float* __restrict__ A_pre, const float* __restrict__ B_pre,
    const float* __restrict__ w0h, const float* __restrict__ w1h,
    const float* __restrict__ bh, const float* __restrict__ evec,
    const unsigned short* __restrict__ WgT,
    const unsigned short* __restrict__ Lst, const int* __restrict__ cnt_g,
    float* __restrict__ Hpart) {
  const int bid = blockIdx.x;
  const int i = bid / NCH;
  const int c = bid - i * NCH;
  const int cnt = cnt_g[i];
  const int base = c * 64;
  if (base >= cnt) return;

  const int lane = threadIdx.x;
  const int quad = lane >> 4;
  const int nl = lane & 15;

  __shared__ __align__(16) unsigned short Rt[64 * 72];  // [pair][k], pad 8
  __shared__ int jpc[64];

  // Per-lane pair data (lane == pair index in chunk).
  int pg = base + lane;
  int jp = (int)Lst[i * NN + (pg < cnt ? pg : base)];
  jpc[lane] = jp;
  float c0 = corr[(i * NN + jp) * 2 + 0];
  float c1 = corr[(i * NN + jp) * 2 + 1];
  const float e00 = evec[0], e11 = evec[1], ebb = evec[2];
  const float e01 = evec[3], e0b = evec[4], e1b = evec[5];
  float var = c0 * c0 * e00 + c1 * c1 * e11 + ebb +
              2.f * (c0 * c1 * e01 + c0 * e0b + c1 * e1b);
  float iv = rsqrtf(var + EPSF);

  // Per-lane k constants (k == lane), pre-scaled by g_r.
  const float pgr = gr[lane];
  const float gw0 = pgr * w0h[lane];
  const float gw1 = pgr * w1h[lane];
  const float gbh = pgr * bh[lane];
  const float pber = ber[lane];

  // B fragments of Wg_lo from the transposed bf16 pack (16B contiguous).
  short8 Bf[2][4];
#pragma unroll
  for (int ks = 0; ks < 2; ++ks)
#pragma unroll
    for (int nt = 0; nt < 4; ++nt)
      __builtin_memcpy(&Bf[ks][nt], &WgT[(nt * 16 + nl) * DD + ks * 32 + quad * 8],
                       16);

  // Epilogue per-lane constants: d = nt*16 + nl.
  float gg4[4], beg4[4], pre4[4];
#pragma unroll
  for (int nt = 0; nt < 4; ++nt) {
    int d = nt * 16 + nl;
    gg4[nt] = gg[d];
    beg4[nt] = beg[d];
    pre4[nt] = A_pre[i * DD + d];
  }

  // R build: 64 rows; broadcast (c0,c1,iv) of pair p via readlane.
#pragma unroll
  for (int p = 0; p < 64; ++p) {
    float sc0 = __shfl(c0, p);
    float sc1 = __shfl(c1, p);
    float siv = __shfl(iv, p);
    float s3 = fmaf(sc0, gw0, fmaf(sc1, gw1, gbh));  // g_r * (raw - u)
    float r = fmaxf(0.f, fmaf(siv, s3, pber));
    Rt[p * 72 + lane] = f2bf(r);
  }
  __syncthreads();  // single wave: just forces the lgkm drain

  float accT[4] = {0.f, 0.f, 0.f, 0.f};

#pragma unroll
  for (int t = 0; t < 4; ++t) {
    short8 a0, a1;
    __builtin_memcpy(&a0, &Rt[(t * 16 + nl) * 72 + quad * 8], 16);
    __builtin_memcpy(&a1, &Rt[(t * 16 + nl) * 72 + 32 + quad * 8], 16);
    float4v acc[4];
#pragma unroll
    for (int nt = 0; nt < 4; ++nt) {
      float4v z = {0.f, 0.f, 0.f, 0.f};
      z = __builtin_amdgcn_mfma_f32_16x16x32_bf16(a0, Bf[0][nt], z, 0, 0, 0);
      z = __builtin_amdgcn_mfma_f32_16x16x32_bf16(a1, Bf[1][nt], z, 0, 0, 0);
      acc[nt] = z;
    }

    int jpr[4];
    float pv[4];
#pragma unroll
    for (int rr = 0; rr < 4; ++rr) {
      int pl = t * 16 + quad * 4 + rr;  // C layout: m = quad*4 + reg
      jpr[rr] = jpc[pl];
      pv[rr] = (base + pl < cnt) ? 1.f : 0.f;
    }
    float y[4][4];
#pragma unroll
    for (int nt = 0; nt < 4; ++nt)
#pragma unroll
      for (int rr = 0; rr < 4; ++rr)
        y[nt][rr] = acc[nt][rr] + pre4[nt] + B_pre[jpr[rr] * DD + nt * 16 + nl];
#pragma unroll
    for (int rr = 0; rr < 4; ++rr) {
      float s = y[0][rr] + y[1][rr] + y[2][rr] + y[3][rr];
      float qq = y[0][rr] * y[0][rr] + y[1][rr] * y[1][rr] +
                 y[2][rr] * y[2][rr] + y[3][rr] * y[3][rr];
#pragma unroll
      for (int m = 1; m < 16; m <<= 1) {
        s += __shfl_xor(s, m);
        qq += __shfl_xor(qq, m);
      }
      float u = s * (1.f / DD);
      float vv = qq * (1.f / DD) - u * u;
      float inv = rsqrtf(vv + EPSF);
      int jj = jpr[rr];
#pragma unroll
      for (int nt = 0; nt < 4; ++nt) {
        float g = fmaf(gg4[nt], (y[nt][rr] - u) * inv, beg4[nt]);
        float gate = __frcp_rn(1.f + __expf(-g));
        float hval = hidden[jj * DD + nt * 16 + nl];
        accT[nt] = fmaf(gate * pv[rr], hval, accT[nt]);
      }
    }
  }

  // Reduce over quads; lanes 0..15 write the 64-channel partial.
#pragma unroll
  for (int nt = 0; nt < 4; ++nt) {
    accT[nt] += __shfl_xor(accT[nt], 16);
    accT[nt] += __shfl_xor(accT[nt], 32);
  }
  if (lane < 16) {
#pragma unroll
    for (int nt = 0; nt < 4; ++nt)
      Hpart[bid * DD + nt * 16 + nl] = accT[nt];
  }
}

// ---------------------------------------------------------------------------
// Final kernel: one wave per row. Sum partials, weight, W_w GEMV, LN, outputs.
// ---------------------------------------------------------------------------
__global__ __launch_bounds__(64) void final_kernel(
    const float* __restrict__ hidden, const float* __restrict__ cn,
    const float* __restrict__ bea, const float* __restrict__ Ww,
    const float* __restrict__ bw, const float* __restrict__ gw,
    const float* __restrict__ bew, const int* __restrict__ cnt_g,
    const float* __restrict__ Hpart, float* __restrict__ out) {
  const int i = blockIdx.x;
  const int d = threadIdx.x;
  const int cnt = cnt_g[i];
  const int nch = (cnt + 63) >> 6;
  float hs = 0.f;
  for (int c = 0; c < nch; ++c) hs += Hpart[(i * NCH + c) * DD + d];
  float tta = fmaxf(bea[0], 0.f);
  float wgt = (tta > 0.f && cnt > 0) ? (1.f / (float)cnt) : (1.f / (float)NN);
  hs *= wgt;  // H_sum[i][d]

  float dotv = bw[d];
#pragma unroll 8
  for (int k = 0; k < DD; ++k) {
    float hk = __shfl(hs, k);
    dotv = fmaf(hk, Ww[k * DD + d], dotv);
  }
  float s = dotv, qq = dotv * dotv;
#pragma unroll
  for (int m = 1; m < 64; m <<= 1) {
    s += __shfl_xor(s, m);
    qq += __shfl_xor(qq, m);
  }
  float u = s * (1.f / DD);
  float var = qq * (1.f / DD) - u * u;
  float inv = rsqrtf(var + EPSF);
  float val = fmaxf(0.f, fmaf(gw[d], (dotv - u) * inv, bew[d]));
  float Cv = val + cn[i * DD + d];
  float Ho = hidden[i * DD + d] + tanhf(Cv);
  out[i * DD + d] = Ho;
  out[NN * DD + i * DD + d] = Cv;
}

extern "C" void kernel_launch(void* const* d_in, const int* in_sizes, int n_in,
                              void* d_out, int out_size, void* d_ws,
                              size_t ws_size, hipStream_t stream) {
  const float* corr = (const float*)d_in[0];
  const int* nei = (const int*)d_in[1];
  // d_in[2] nei_num: unused by the reference math
  const float* hidden = (const float*)d_in[3];
  const float* cn = (const float*)d_in[4];
  const float* Wr = (const float*)d_in[5];
  const float* br = (const float*)d_in[6];
  const float* gr = (const float*)d_in[7];
  const float* ber = (const float*)d_in[8];
  const float* Wg = (const float*)d_in[9];
  const float* bg = (const float*)d_in[10];
  const float* gg = (const float*)d_in[11];
  const float* beg = (const float*)d_in[12];
  // d_in[13..15] W_a/b_a/g_a: cancel analytically (LN over size-1 axis)
  const float* bea = (const float*)d_in[16];
  const float* Ww = (const float*)d_in[17];
  const float* bw = (const float*)d_in[18];
  const float* gw = (const float*)d_in[19];
  const float* bew = (const float*)d_in[20];
  float* out = (float*)d_out;

  float* ws = (float*)d_ws;
  // float-offset layout (all 16B aligned):
  float* A_pre = ws;                        // 768*64 = 49152
  float* B_pre = ws + 49152;                // 49152
  float* w0h = ws + 98304;                  // 64
  float* w1h = ws + 98368;                  // 64
  float* bh = ws + 98432;                   // 64
  float* evec = ws + 98496;                 // 6 (pad to 16)
  unsigned short* WgT = (unsigned short*)(ws + 98512);   // 4096 shorts
  int* cnt_g = (int*)(ws + 100560);         // 768
  unsigned short* Lst = (unsigned short*)(ws + 101328);  // 768*768 shorts
  float* Hpart = ws + 396240;               // 768*12*64 = 589824

  prep_kernel<<<NN + 1 + NN / 4, 256, 0, stream>>>(
      hidden, Wg, bg, Wr, br, nei, A_pre, B_pre, w0h, w1h, bh, evec, WgT, Lst,
      cnt_g);
  pair_kernel<<<NN * NCH, 64, 0, stream>>>(corr, hidden, gr, ber, gg, beg,
                                           A_pre, B_pre, w0h, w1h, bh, evec,
                                           WgT, Lst, cnt_g, Hpart);
  final_kernel<<<NN, 64, 0, stream>>>(hidden, cn, bea, Ww, bw, gw, bew, cnt_g,
                                      Hpart, out);
}